// Round 3
// baseline (543.019 us; speedup 1.0000x reference)
//
#include <hip/hip_runtime.h>

// N=384 spatial, C=128 channels. Two tri-mul passes (outgoing, incoming).
// ws layout: [12 swizzled bf16 weight mats | a_t | b_t | g | zn/p_t(shared)],
// big bufs NN*128 bf16 each. Total ~144.4 MiB.

constexpr int NS = 384;
constexpr int NN = NS * NS;

using bf16x8 = __attribute__((ext_vector_type(8))) __bf16;
using f32x4  = __attribute__((ext_vector_type(4))) float;

__device__ inline void load16_to_lds(const __bf16* g, __bf16* lds) {
  auto* gp = reinterpret_cast<const __attribute__((address_space(1))) unsigned int*>(
      reinterpret_cast<uintptr_t>(g));
  auto* lp = reinterpret_cast<__attribute__((address_space(3))) unsigned int*>(
      reinterpret_cast<uintptr_t>(lds));
  __builtin_amdgcn_global_load_lds(gp, lp, 16, 0, 0);
}

__device__ inline float sigmoidf_fast(float x) {
  float e = __expf(-x);
  return __builtin_amdgcn_rcpf(1.0f + e);
}

// ---------------- K0: weight fp32 -> bf16, swizzled to MFMA fragment order ------------
// Fragment slot layout per matrix: idx = ((s*8 + t)*64 + lane)*8 + j  holds
// W[32*s + 8*(lane>>4) + j][16*t + (lane&15)].
__global__ __launch_bounds__(256) void prep_weights(
    const float* __restrict__ w_ag, const float* __restrict__ w_ap,
    const float* __restrict__ w_bg, const float* __restrict__ w_bp,
    const float* __restrict__ w_g,  const float* __restrict__ w_z,
    __bf16* __restrict__ wsw)
{
  int gid  = blockIdx.x * 256 + threadIdx.x;   // 96*256 = 24576 = 12*2048
  int mat  = gid >> 11;
  int slot = gid & 2047;
  int lane = slot & 63;
  int tb   = (slot >> 6) & 7;
  int s    = slot >> 9;
  int pass = mat / 6, which = mat % 6;
  const float* W;
  switch (which) {
    case 0: W = w_ag; break; case 1: W = w_ap; break; case 2: W = w_bg; break;
    case 3: W = w_bp; break; case 4: W = w_g;  break; default: W = w_z;
  }
  W += pass * 16384;
  int n0 = tb * 16 + (lane & 15);
  int k0 = s * 32 + (lane >> 4) * 8;
  __bf16* dst = wsw + ((size_t)mat * 2048 + slot) * 8;
#pragma unroll
  for (int j = 0; j < 8; ++j) dst[j] = (__bf16)W[(k0 + j) * 128 + n0];
}

// ---------------- K1: LayerNorm z -> zn bf16 ------------------------------------------
// mode 0: native row order (q == p). mode 1: q-order = transposed enumeration:
// zn[q = i*NS + j] = LN(z[p = j*NS + i])  -> contiguous writes, column reads.
__global__ __launch_bounds__(256) void ln_kernel(
    const float* __restrict__ zsrc, const float* __restrict__ lnw, const float* __restrict__ lnb,
    __bf16* __restrict__ zn, int mode)
{
  int tid = threadIdx.x;
  int row = tid >> 2, q = tid & 3;
  size_t zoff, qidx;
  if (mode == 0) { qidx = (size_t)blockIdx.x * 64 + row; zoff = qidx * 128; }
  else {
    int i = blockIdx.x / 6;
    int j = (blockIdx.x % 6) * 64 + row;
    zoff = ((size_t)j * NS + i) * 128;
    qidx = (size_t)i * NS + j;
  }
  const float4* zp = (const float4*)(zsrc + zoff) + q * 8;
  float4 v[8];
#pragma unroll
  for (int u = 0; u < 8; ++u) v[u] = zp[u];
  float s1 = 0.f, s2 = 0.f;
#pragma unroll
  for (int u = 0; u < 8; ++u) {
    float4 t = v[u];
    s1 += t.x + t.y + t.z + t.w;
    s2 += t.x * t.x + t.y * t.y + t.z * t.z + t.w * t.w;
  }
  s1 += __shfl_xor(s1, 1); s2 += __shfl_xor(s2, 1);
  s1 += __shfl_xor(s1, 2); s2 += __shfl_xor(s2, 2);
  float mean = s1 * (1.0f / 128.0f);
  float var  = s2 * (1.0f / 128.0f) - mean * mean;
  float rstd = rsqrtf(var + 1e-5f);
  bf16x8 o[4];
#pragma unroll
  for (int u = 0; u < 8; ++u) {
    int c0 = q * 32 + u * 4;
    float4 t  = v[u];
    float4 w4 = *(const float4*)(lnw + c0);
    float4 b4 = *(const float4*)(lnb + c0);
    o[u >> 1][(u & 1) * 4 + 0] = (__bf16)((t.x - mean) * rstd * w4.x + b4.x);
    o[u >> 1][(u & 1) * 4 + 1] = (__bf16)((t.y - mean) * rstd * w4.y + b4.y);
    o[u >> 1][(u & 1) * 4 + 2] = (__bf16)((t.z - mean) * rstd * w4.z + b4.z);
    o[u >> 1][(u & 1) * 4 + 3] = (__bf16)((t.w - mean) * rstd * w4.w + b4.w);
  }
  __bf16* dst = zn + qidx * 128 + q * 32;
#pragma unroll
  for (int u = 0; u < 4; ++u) *(bf16x8*)(dst + u * 8) = o[u];
}

// ---------------- K2: projections as tiled GEMM ---------------------------------------
// grid (1152, 3): blockIdx.y = product (0=a, 1=b, 2=g). M-tile = 128 positions
// (q-order), N = 128 c_out (x2 matrices for a/b), K = 128.
// zn tile staged in LDS (XOR chunk swizzle); weight frags direct to registers.
// Output a/b: c-major a_t[c][q] wide stores; g: row-major [p][c] (mode-aware addr).
__global__ __launch_bounds__(256, 2) void proj2_kernel(
    const __bf16* __restrict__ zn, const __bf16* __restrict__ wsw5,
    const float* __restrict__ bag, const float* __restrict__ bap,
    const float* __restrict__ bbg, const float* __restrict__ bbp,
    const float* __restrict__ bgg,
    __bf16* __restrict__ a_t, __bf16* __restrict__ b_t, __bf16* __restrict__ g_out,
    int mode)
{
  __shared__ __bf16 znlds[128 * 128];   // 32 KB, swizzled: row r slot s holds chunk s^(r&15)
  __shared__ __bf16 alds[128 * 128];    // 32 KB epilogue transpose buffer

  const int tid = threadIdx.x;
  const int wv = tid >> 6, lane = tid & 63;
  const int lm = lane & 15, lq = lane >> 4;
  const int prod = blockIdx.y;
  const bool twomat = (prod != 2);
  const __bf16* wbase = wsw5 + (size_t)prod * 2 * 16384;
  const size_t pbase = (size_t)blockIdx.x * 128;

  // ---- stage zn tile (128 rows x 256B) via global_load_lds, XOR swizzle ----
  {
    const __bf16* zsrc = zn + pbase * 128;
    int lrow = lane >> 4, lsl = lane & 15;
#pragma unroll
    for (int t = 0; t < 8; ++t) {
      int rbase = (wv * 8 + t) * 4;
      int row = rbase + lrow;
      int chunk = lsl ^ (row & 15);
      load16_to_lds(zsrc + (size_t)row * 128 + chunk * 8, znlds + rbase * 128);
    }
  }

  // ---- weight fragments to registers (wave-private n-tiles n0, n0+1) ----
  const int n0 = 2 * wv;
  bf16x8 wf[2][2][4];
#pragma unroll
  for (int n2 = 0; n2 < 2; ++n2)
#pragma unroll
    for (int s = 0; s < 4; ++s) {
      wf[n2][0][s] = *(const bf16x8*)(wbase + ((size_t)((s * 8 + n0 + n2) * 64 + lane)) * 8);
      if (twomat)
        wf[n2][1][s] = *(const bf16x8*)(wbase + 16384 + ((size_t)((s * 8 + n0 + n2) * 64 + lane)) * 8);
    }
  const float* pbA = (prod == 0) ? bag : (prod == 1) ? bbg : bgg;
  const float* pbB = (prod == 0) ? bap : bbp;
  float bA[2], bB[2];
#pragma unroll
  for (int n2 = 0; n2 < 2; ++n2) {
    bA[n2] = pbA[(n0 + n2) * 16 + lm];
    bB[n2] = twomat ? pbB[(n0 + n2) * 16 + lm] : 0.f;
  }

  f32x4 acc[8][2][2];
#pragma unroll
  for (int m = 0; m < 8; ++m)
#pragma unroll
    for (int n2 = 0; n2 < 2; ++n2)
#pragma unroll
      for (int mt = 0; mt < 2; ++mt) acc[m][n2][mt] = {0.f, 0.f, 0.f, 0.f};

  __syncthreads();   // drains vmcnt for global_load_lds

  // ---- main MFMA loop ----
#pragma unroll
  for (int m = 0; m < 8; ++m) {
    bf16x8 zf[4];
#pragma unroll
    for (int s = 0; s < 4; ++s) {
      int slot = (4 * s + lq) ^ lm;
      zf[s] = *(const bf16x8*)(znlds + (m * 16 + lm) * 128 + slot * 8);
    }
#pragma unroll
    for (int s = 0; s < 4; ++s)
#pragma unroll
      for (int n2 = 0; n2 < 2; ++n2) {
        acc[m][n2][0] = __builtin_amdgcn_mfma_f32_16x16x32_bf16(zf[s], wf[n2][0][s], acc[m][n2][0], 0, 0, 0);
        if (twomat)
          acc[m][n2][1] = __builtin_amdgcn_mfma_f32_16x16x32_bf16(zf[s], wf[n2][1][s], acc[m][n2][1], 0, 0, 0);
      }
  }

  // ---- epilogue ----
  if (prod < 2) {
    // a/b: value = (proj + bB) * sigmoid(gate + bA); transpose to c-major via alds.
    // alds row = c, slot = (pos>>3) ^ (c&15), offset pos&7 (pairs packed, 4B writes).
#pragma unroll
    for (int m = 0; m < 8; ++m)
#pragma unroll
      for (int n2 = 0; n2 < 2; ++n2) {
        int c = (n0 + n2) * 16 + lm;
#pragma unroll
        for (int rr = 0; rr < 2; ++rr) {
          int pos = m * 16 + 4 * lq + 2 * rr;
          float g0 = acc[m][n2][0][2 * rr]     + bA[n2];
          float g1 = acc[m][n2][0][2 * rr + 1] + bA[n2];
          float p0 = acc[m][n2][1][2 * rr]     + bB[n2];
          float p1 = acc[m][n2][1][2 * rr + 1] + bB[n2];
          union { __bf16 h[2]; unsigned u; } pk;
          pk.h[0] = (__bf16)(p0 * sigmoidf_fast(g0));
          pk.h[1] = (__bf16)(p1 * sigmoidf_fast(g1));
          int addr = c * 128 + (((pos >> 3) ^ (c & 15)) << 3) + (pos & 7);
          *(unsigned*)(&alds[addr]) = pk.u;
        }
      }
    __syncthreads();
    __bf16* outp = (prod == 0) ? a_t : b_t;
    int c = tid & 127, half = tid >> 7;
    __bf16* dst = outp + (size_t)c * NN + pbase;
#pragma unroll
    for (int jj = 0; jj < 8; ++jj) {
      int j = half * 8 + jj;                 // FIXED: cover all 16 chunks (128 positions)
      bf16x8 vv = *(const bf16x8*)(&alds[c * 128 + ((j ^ (c & 15)) << 3)]);
      *(bf16x8*)(dst + j * 8) = vv;
    }
  } else {
    // g: row-major [p][c]; alds row = pos, slot = (c>>3) ^ (pos&15), offset c&7.
#pragma unroll
    for (int m = 0; m < 8; ++m)
#pragma unroll
      for (int n2 = 0; n2 < 2; ++n2) {
        int c = (n0 + n2) * 16 + lm;
#pragma unroll
        for (int r = 0; r < 4; ++r) {
          int pos = m * 16 + 4 * lq + r;
          float gv = sigmoidf_fast(acc[m][n2][0][r] + bA[n2]);
          int addr = pos * 128 + (((c >> 3) ^ (pos & 15)) << 3) + (c & 7);
          alds[addr] = (__bf16)gv;
        }
      }
    __syncthreads();
    int pos = tid & 127, half = tid >> 7;
    size_t q = pbase + pos;
    size_t gp;
    if (mode == 0) gp = q;
    else { int i = (int)(q / NS); int j = (int)(q % NS); gp = (size_t)j * NS + i; }
    __bf16* dst = g_out + gp * 128;
#pragma unroll
    for (int jj = 0; jj < 8; ++jj) {
      int j = half * 8 + jj;                 // FIXED: cover all 16 chunks (128 channels)
      *(bf16x8*)(dst + j * 8) = *(const bf16x8*)(&alds[pos * 128 + ((j ^ (pos & 15)) << 3)]);
    }
  }
}

// ---------------- K3: triangle einsum, per-channel 384x384x384 NT GEMM ----------------
__global__ __launch_bounds__(256) void tri_kernel(
    const __bf16* __restrict__ a_t, const __bf16* __restrict__ b_t, __bf16* __restrict__ p_t)
{
  __shared__ __bf16 As[128 * 64];
  __shared__ __bf16 Bs[128 * 64];
  int c  = blockIdx.z;
  int i0 = blockIdx.x * 128, k0 = blockIdx.y * 128;
  const __bf16* Ab = a_t + (size_t)c * NN;
  const __bf16* Bb = b_t + (size_t)c * NN;
  int tid = threadIdx.x, wv = tid >> 6, lane = tid & 63;
  int lm = lane & 15, lq = lane >> 4;
  int lrow = lane >> 3;
  int lsl  = lane & 7;
  int lch  = lsl ^ lrow;
  f32x4 acc[4][4];
#pragma unroll
  for (int mi = 0; mi < 4; ++mi)
#pragma unroll
    for (int ni = 0; ni < 4; ++ni) acc[mi][ni] = {0.f, 0.f, 0.f, 0.f};
  const int rowA_half = 64 * (wv & 1), colB_half = 64 * (wv >> 1);

  for (int kk = 0; kk < 384; kk += 64) {
    __syncthreads();
#pragma unroll
    for (int v = 0; v < 4; ++v) {
      int rgrp = 4 * wv + v;
      int r = 8 * rgrp + lrow;
      load16_to_lds(Ab + (size_t)(i0 + r) * NS + kk + lch * 8, As + rgrp * 512);
      load16_to_lds(Bb + (size_t)(k0 + r) * NS + kk + lch * 8, Bs + rgrp * 512);
    }
    __syncthreads();
#pragma unroll
    for (int s = 0; s < 2; ++s) {
      bf16x8 bfr[4], afr[4];
#pragma unroll
      for (int ni = 0; ni < 4; ++ni)
        bfr[ni] = *(const bf16x8*)(Bs + (colB_half + 16 * ni + lm) * 64 +
                                   ((4 * s + lq) ^ (lm & 7)) * 8);
#pragma unroll
      for (int mi = 0; mi < 4; ++mi)
        afr[mi] = *(const bf16x8*)(As + (rowA_half + 16 * mi + lm) * 64 +
                                   ((4 * s + lq) ^ (lm & 7)) * 8);
#pragma unroll
      for (int mi = 0; mi < 4; ++mi)
#pragma unroll
        for (int ni = 0; ni < 4; ++ni)
          acc[mi][ni] = __builtin_amdgcn_mfma_f32_16x16x32_bf16(afr[mi], bfr[ni], acc[mi][ni], 0, 0, 0);
    }
  }
#pragma unroll
  for (int mi = 0; mi < 4; ++mi)
#pragma unroll
    for (int ni = 0; ni < 4; ++ni)
#pragma unroll
      for (int r = 0; r < 4; ++r) {
        int row = i0 + rowA_half + 16 * mi + 4 * lq + r;
        int col = k0 + colB_half + 16 * ni + lm;
        p_t[(size_t)c * NN + (size_t)row * NS + col] = (__bf16)acc[mi][ni][r];
      }
}

// ---------------- K4: LN over c, @w_z + b_z, * g, + z residual ------------------------
__global__ __launch_bounds__(256) void out_kernel(
    const __bf16* __restrict__ p_t, const __bf16* __restrict__ g_in,
    const float* __restrict__ z_in, float* __restrict__ z_out,
    const float* __restrict__ lnw, const float* __restrict__ lnb,
    const __bf16* __restrict__ wz, const float* __restrict__ bz)
{
  __shared__ __bf16 pl[64][136];
  int tid = threadIdx.x;
  size_t base = (size_t)blockIdx.x * 64;

  {
    int c2 = tid >> 1, hf = tid & 1;
    const __bf16* src = p_t + (size_t)c2 * NN + base + hf * 32;
    bf16x8 v0 = ((const bf16x8*)src)[0];
    bf16x8 v1 = ((const bf16x8*)src)[1];
    bf16x8 v2 = ((const bf16x8*)src)[2];
    bf16x8 v3 = ((const bf16x8*)src)[3];
#pragma unroll
    for (int j = 0; j < 8; ++j) pl[hf * 32 + j][c2] = v0[j];
#pragma unroll
    for (int j = 0; j < 8; ++j) pl[hf * 32 + 8 + j][c2] = v1[j];
#pragma unroll
    for (int j = 0; j < 8; ++j) pl[hf * 32 + 16 + j][c2] = v2[j];
#pragma unroll
    for (int j = 0; j < 8; ++j) pl[hf * 32 + 24 + j][c2] = v3[j];
  }
  __syncthreads();

  {
    int row = tid >> 2, q = tid & 3;
    bf16x8 pv[4];
#pragma unroll
    for (int s = 0; s < 4; ++s) pv[s] = *(const bf16x8*)(&pl[row][q * 32 + 8 * s]);
    float s1 = 0.f, s2 = 0.f;
#pragma unroll
    for (int s = 0; s < 4; ++s)
#pragma unroll
      for (int j = 0; j < 8; ++j) { float f = (float)pv[s][j]; s1 += f; s2 += f * f; }
    s1 += __shfl_xor(s1, 1); s2 += __shfl_xor(s2, 1);
    s1 += __shfl_xor(s1, 2); s2 += __shfl_xor(s2, 2);
    float mean = s1 * (1.0f / 128.0f);
    float var  = s2 * (1.0f / 128.0f) - mean * mean;
    float rstd = rsqrtf(var + 1e-5f);
#pragma unroll
    for (int s = 0; s < 4; ++s) {
#pragma unroll
      for (int j = 0; j < 8; ++j) {
        int cc = q * 32 + 8 * s + j;
        float f = ((float)pv[s][j] - mean) * rstd * lnw[cc] + lnb[cc];
        pv[s][j] = (__bf16)f;
      }
      *(bf16x8*)(&pl[row][q * 32 + 8 * s]) = pv[s];
    }
  }
  __syncthreads();

  int wv = tid >> 6, lane = tid & 63, lm = lane & 15, lq = lane >> 4;
  bf16x8 wzf[2][4];
  float bzv[2];
#pragma unroll
  for (int nbi = 0; nbi < 2; ++nbi) {
    int nb = 2 * wv + nbi;
    bzv[nbi] = bz[16 * nb + lm];
#pragma unroll
    for (int s = 0; s < 4; ++s)
      wzf[nbi][s] = *(const bf16x8*)(wz + ((size_t)((s * 8 + nb) * 64 + lane)) * 8);
  }
#pragma unroll
  for (int mt = 0; mt < 4; ++mt) {
    bf16x8 af[4];
#pragma unroll
    for (int s = 0; s < 4; ++s)
      af[s] = *(const bf16x8*)(&pl[16 * mt + lm][32 * s + 8 * lq]);
#pragma unroll
    for (int nbi = 0; nbi < 2; ++nbi) {
      f32x4 acc = {0.f, 0.f, 0.f, 0.f};
#pragma unroll
      for (int s = 0; s < 4; ++s)
        acc = __builtin_amdgcn_mfma_f32_16x16x32_bf16(af[s], wzf[nbi][s], acc, 0, 0, 0);
      int cz = 16 * (2 * wv + nbi) + lm;
#pragma unroll
      for (int r = 0; r < 4; ++r) {
        int pos = 16 * mt + 4 * lq + r;
        size_t idx = (base + pos) * 128 + cz;
        float gv  = (float)g_in[idx];
        float res = (acc[r] + bzv[nbi]) * gv + z_in[idx];
        z_out[idx] = res;
      }
    }
  }
}

extern "C" void kernel_launch(void* const* d_in, const int* in_sizes, int n_in,
                              void* d_out, int out_size, void* d_ws, size_t ws_size,
                              hipStream_t stream) {
  (void)in_sizes; (void)n_in; (void)out_size; (void)ws_size;
  const float* z        = (const float*)d_in[0];
  const float* ln_in_w  = (const float*)d_in[1];
  const float* ln_in_b  = (const float*)d_in[2];
  const float* w_ag     = (const float*)d_in[3];
  const float* b_ag     = (const float*)d_in[4];
  const float* w_ap     = (const float*)d_in[5];
  const float* b_ap     = (const float*)d_in[6];
  const float* w_bg     = (const float*)d_in[7];
  const float* b_bg     = (const float*)d_in[8];
  const float* w_bp     = (const float*)d_in[9];
  const float* b_bp     = (const float*)d_in[10];
  const float* ln_out_w = (const float*)d_in[11];
  const float* ln_out_b = (const float*)d_in[12];
  const float* w_z      = (const float*)d_in[13];
  const float* b_z      = (const float*)d_in[14];
  const float* w_g      = (const float*)d_in[15];
  const float* b_g      = (const float*)d_in[16];
  float* out = (float*)d_out;

  __bf16* wsw  = (__bf16*)d_ws;             // 12 * 16384 elements
  __bf16* a_t  = wsw + 12 * 16384;
  __bf16* b_t  = a_t + (size_t)NN * 128;
  __bf16* g_b  = b_t + (size_t)NN * 128;
  __bf16* znpt = g_b + (size_t)NN * 128;    // zn during proj, p_t after tri

  prep_weights<<<96, 256, 0, stream>>>(w_ag, w_ap, w_bg, w_bp, w_g, w_z, wsw);

  for (int idx = 0; idx < 2; ++idx) {
    const float* zsrc = (idx == 0) ? z : out;
    const __bf16* wsw5 = wsw + (size_t)idx * 6 * 16384;
    ln_kernel<<<2304, 256, 0, stream>>>(zsrc, ln_in_w + idx * 128, ln_in_b + idx * 128,
                                        znpt, idx);
    proj2_kernel<<<dim3(1152, 3), 256, 0, stream>>>(
        znpt, wsw5,
        b_ag + idx * 128, b_ap + idx * 128, b_bg + idx * 128, b_bp + idx * 128,
        b_g + idx * 128, a_t, b_t, g_b, idx);
    tri_kernel<<<dim3(3, 3, 128), 256, 0, stream>>>(a_t, b_t, znpt);
    out_kernel<<<2304, 256, 0, stream>>>(
        znpt, g_b, zsrc, out, ln_out_w + idx * 128, ln_out_b + idx * 128,
        wsw5 + 5 * 16384, b_z + idx * 128);
  }
}

// Round 4
// 520.017 us; speedup vs baseline: 1.0442x; 1.0442x over previous
//
#include <hip/hip_runtime.h>

// N=384 spatial, C=128 channels. Two tri-mul passes (outgoing, incoming).
// ws layout: [12 swizzled bf16 weight mats | a_t | b_t | g | zn/p_t(shared)],
// big bufs NN*128 bf16 each. Total ~144.4 MiB.

constexpr int NS = 384;
constexpr int NN = NS * NS;

using bf16x8 = __attribute__((ext_vector_type(8))) __bf16;
using f32x4  = __attribute__((ext_vector_type(4))) float;

__device__ inline void load16_to_lds(const __bf16* g, __bf16* lds) {
  auto* gp = reinterpret_cast<const __attribute__((address_space(1))) unsigned int*>(
      reinterpret_cast<uintptr_t>(g));
  auto* lp = reinterpret_cast<__attribute__((address_space(3))) unsigned int*>(
      reinterpret_cast<uintptr_t>(lds));
  __builtin_amdgcn_global_load_lds(gp, lp, 16, 0, 0);
}

__device__ inline float sigmoidf_fast(float x) {
  float e = __expf(-x);
  return __builtin_amdgcn_rcpf(1.0f + e);
}

// ---------------- K0: weight fp32 -> bf16, swizzled to MFMA fragment order ------------
// Fragment slot layout per matrix: idx = ((s*8 + t)*64 + lane)*8 + j  holds
// W[32*s + 8*(lane>>4) + j][16*t + (lane&15)].
__global__ __launch_bounds__(256) void prep_weights(
    const float* __restrict__ w_ag, const float* __restrict__ w_ap,
    const float* __restrict__ w_bg, const float* __restrict__ w_bp,
    const float* __restrict__ w_g,  const float* __restrict__ w_z,
    __bf16* __restrict__ wsw)
{
  int gid  = blockIdx.x * 256 + threadIdx.x;   // 96*256 = 24576 = 12*2048
  int mat  = gid >> 11;
  int slot = gid & 2047;
  int lane = slot & 63;
  int tb   = (slot >> 6) & 7;
  int s    = slot >> 9;
  int pass = mat / 6, which = mat % 6;
  const float* W;
  switch (which) {
    case 0: W = w_ag; break; case 1: W = w_ap; break; case 2: W = w_bg; break;
    case 3: W = w_bp; break; case 4: W = w_g;  break; default: W = w_z;
  }
  W += pass * 16384;
  int n0 = tb * 16 + (lane & 15);
  int k0 = s * 32 + (lane >> 4) * 8;
  __bf16* dst = wsw + ((size_t)mat * 2048 + slot) * 8;
#pragma unroll
  for (int j = 0; j < 8; ++j) dst[j] = (__bf16)W[(k0 + j) * 128 + n0];
}

// ---------------- K1: LayerNorm z -> zn bf16 ------------------------------------------
// mode 0: native row order (q == p). mode 1: q-order = transposed enumeration:
// zn[q = i*NS + j] = LN(z[p = j*NS + i])  -> contiguous writes, column reads.
__global__ __launch_bounds__(256) void ln_kernel(
    const float* __restrict__ zsrc, const float* __restrict__ lnw, const float* __restrict__ lnb,
    __bf16* __restrict__ zn, int mode)
{
  int tid = threadIdx.x;
  int row = tid >> 2, q = tid & 3;
  size_t zoff, qidx;
  if (mode == 0) { qidx = (size_t)blockIdx.x * 64 + row; zoff = qidx * 128; }
  else {
    int i = blockIdx.x / 6;
    int j = (blockIdx.x % 6) * 64 + row;
    zoff = ((size_t)j * NS + i) * 128;
    qidx = (size_t)i * NS + j;
  }
  const float4* zp = (const float4*)(zsrc + zoff) + q * 8;
  float4 v[8];
#pragma unroll
  for (int u = 0; u < 8; ++u) v[u] = zp[u];
  float s1 = 0.f, s2 = 0.f;
#pragma unroll
  for (int u = 0; u < 8; ++u) {
    float4 t = v[u];
    s1 += t.x + t.y + t.z + t.w;
    s2 += t.x * t.x + t.y * t.y + t.z * t.z + t.w * t.w;
  }
  s1 += __shfl_xor(s1, 1); s2 += __shfl_xor(s2, 1);
  s1 += __shfl_xor(s1, 2); s2 += __shfl_xor(s2, 2);
  float mean = s1 * (1.0f / 128.0f);
  float var  = s2 * (1.0f / 128.0f) - mean * mean;
  float rstd = rsqrtf(var + 1e-5f);
  bf16x8 o[4];
#pragma unroll
  for (int u = 0; u < 8; ++u) {
    int c0 = q * 32 + u * 4;
    float4 t  = v[u];
    float4 w4 = *(const float4*)(lnw + c0);
    float4 b4 = *(const float4*)(lnb + c0);
    o[u >> 1][(u & 1) * 4 + 0] = (__bf16)((t.x - mean) * rstd * w4.x + b4.x);
    o[u >> 1][(u & 1) * 4 + 1] = (__bf16)((t.y - mean) * rstd * w4.y + b4.y);
    o[u >> 1][(u & 1) * 4 + 2] = (__bf16)((t.z - mean) * rstd * w4.z + b4.z);
    o[u >> 1][(u & 1) * 4 + 3] = (__bf16)((t.w - mean) * rstd * w4.w + b4.w);
  }
  __bf16* dst = zn + qidx * 128 + q * 32;
#pragma unroll
  for (int u = 0; u < 4; ++u) *(bf16x8*)(dst + u * 8) = o[u];
}

// ---------------- K2: projections, tile-looped + double-buffered ----------------------
// 864 blocks = 3 products x 288 groups; id = prod*288 + grp keeps the 3 products of a
// group on the same XCD (288 % 8 == 0) for zn L2 reuse. Each block loops 8 M64-tiles.
// a/b: acc = mfma(zn, w) -> lane owns 4 consecutive positions  -> 8B stores, c-major.
// g:   acc = mfma(w, zn) -> lane owns 4 consecutive channels   -> 8B stores, row-major.
__global__ __launch_bounds__(256, 2) void proj3_kernel(
    const __bf16* __restrict__ zn, const __bf16* __restrict__ wsw5,
    const float* __restrict__ bag, const float* __restrict__ bap,
    const float* __restrict__ bbg, const float* __restrict__ bbp,
    const float* __restrict__ bgg,
    __bf16* __restrict__ a_t, __bf16* __restrict__ b_t, __bf16* __restrict__ g_out,
    int mode)
{
  __shared__ __bf16 zl[2][64 * 128];   // 2 x 16 KB, swizzled: row r slot s = chunk s^(r&15)
  const int tid = threadIdx.x;
  const int wv = tid >> 6, lane = tid & 63;
  const int lm = lane & 15, lq = lane >> 4;
  const int id = blockIdx.x;
  const int prod = id / 288;
  const int grp  = id % 288;
  const bool twomat = (prod != 2);
  const __bf16* wbase = wsw5 + (size_t)prod * 2 * 16384;

  // ---- weight fragments (once per block) ----
  bf16x8 wf[2][2][4];
#pragma unroll
  for (int n2 = 0; n2 < 2; ++n2)
#pragma unroll
    for (int s = 0; s < 4; ++s) {
      wf[n2][0][s] = *(const bf16x8*)(wbase + ((size_t)((s * 8 + 2 * wv + n2) * 64 + lane)) * 8);
      if (twomat)
        wf[n2][1][s] = *(const bf16x8*)(wbase + 16384 + ((size_t)((s * 8 + 2 * wv + n2) * 64 + lane)) * 8);
    }
  const float* pbA = (prod == 0) ? bag : (prod == 1) ? bbg : bgg;
  const float* pbB = (prod == 0) ? bap : bbp;
  float bA[2] = {0.f, 0.f}, bB[2] = {0.f, 0.f};
  f32x4 bG[2];
#pragma unroll
  for (int n2 = 0; n2 < 2; ++n2) {
    if (twomat) {
      bA[n2] = pbA[(2 * wv + n2) * 16 + lm];
      bB[n2] = pbB[(2 * wv + n2) * 16 + lm];
    } else {
      bG[n2] = *(const f32x4*)(bgg + (2 * wv + n2) * 16 + 4 * lq);
    }
  }

  const int lrow = lane >> 4, lsl = lane & 15;
  // stage one 64x128 tile (16 KB) into buf
#define STAGE(T, BUF)                                                          \
  {                                                                            \
    const __bf16* src = zn + (size_t)(T) * 64 * 128;                           \
    _Pragma("unroll")                                                          \
    for (int t = 0; t < 4; ++t) {                                              \
      int rbase = wv * 16 + t * 4;                                             \
      int row = rbase + lrow;                                                  \
      int chunk = lsl ^ (row & 15);                                            \
      load16_to_lds(src + (size_t)row * 128 + chunk * 8, (BUF) + rbase * 128); \
    }                                                                          \
  }

  STAGE(grp * 8, zl[0]);

  for (int tt = 0; tt < 8; ++tt) {
    const int T = grp * 8 + tt;
    const __bf16* buf = zl[tt & 1];
    __syncthreads();                     // tile tt staged; prev tile's LDS reads done
    if (tt < 7) STAGE(T + 1, zl[(tt & 1) ^ 1]);

    f32x4 acc[4][2][2];
#pragma unroll
    for (int m = 0; m < 4; ++m)
#pragma unroll
      for (int n2 = 0; n2 < 2; ++n2) {
        acc[m][n2][0] = {0.f, 0.f, 0.f, 0.f};
        acc[m][n2][1] = {0.f, 0.f, 0.f, 0.f};
      }

    const size_t Tbase = (size_t)T * 64;
    if (twomat) {
#pragma unroll
      for (int m = 0; m < 4; ++m) {
        bf16x8 zf[4];
#pragma unroll
        for (int s = 0; s < 4; ++s)
          zf[s] = *(const bf16x8*)(buf + (m * 16 + lm) * 128 + (((4 * s + lq) ^ lm) << 3));
#pragma unroll
        for (int s = 0; s < 4; ++s)
#pragma unroll
          for (int n2 = 0; n2 < 2; ++n2) {
            acc[m][n2][0] = __builtin_amdgcn_mfma_f32_16x16x32_bf16(zf[s], wf[n2][0][s], acc[m][n2][0], 0, 0, 0);
            acc[m][n2][1] = __builtin_amdgcn_mfma_f32_16x16x32_bf16(zf[s], wf[n2][1][s], acc[m][n2][1], 0, 0, 0);
          }
      }
      __bf16* outp = (prod == 0) ? a_t : b_t;
#pragma unroll
      for (int m = 0; m < 4; ++m)
#pragma unroll
        for (int n2 = 0; n2 < 2; ++n2) {
          int c = (2 * wv + n2) * 16 + lm;
          union { __bf16 h[4]; uint2 u; } pk;
#pragma unroll
          for (int r = 0; r < 4; ++r) {
            float gg = acc[m][n2][0][r] + bA[n2];
            float pp = acc[m][n2][1][r] + bB[n2];
            pk.h[r] = (__bf16)(pp * sigmoidf_fast(gg));
          }
          *(uint2*)(outp + (size_t)c * NN + Tbase + 16 * m + 4 * lq) = pk.u;
        }
    } else {
#pragma unroll
      for (int m = 0; m < 4; ++m) {
        bf16x8 zf[4];
#pragma unroll
        for (int s = 0; s < 4; ++s)
          zf[s] = *(const bf16x8*)(buf + (m * 16 + lm) * 128 + (((4 * s + lq) ^ lm) << 3));
#pragma unroll
        for (int s = 0; s < 4; ++s)
#pragma unroll
          for (int n2 = 0; n2 < 2; ++n2)
            acc[m][n2][0] = __builtin_amdgcn_mfma_f32_16x16x32_bf16(wf[n2][0][s], zf[s], acc[m][n2][0], 0, 0, 0);
      }
#pragma unroll
      for (int m = 0; m < 4; ++m)
#pragma unroll
        for (int n2 = 0; n2 < 2; ++n2) {
          size_t q = Tbase + 16 * m + lm;
          size_t gp;
          if (mode == 0) gp = q;
          else { int i = (int)(q / NS); int j = (int)(q % NS); gp = (size_t)j * NS + i; }
          int c0 = (2 * wv + n2) * 16 + 4 * lq;
          union { __bf16 h[4]; uint2 u; } pk;
#pragma unroll
          for (int r = 0; r < 4; ++r)
            pk.h[r] = (__bf16)sigmoidf_fast(acc[m][n2][0][r] + bG[n2][r]);
          *(uint2*)(g_out + gp * 128 + c0) = pk.u;
        }
    }
  }
#undef STAGE
}

// ---------------- K3: triangle einsum, per-channel 384x384x384 NT GEMM ----------------
// Linear grid 1152; id%8 = XCD; all 9 tiles of a channel share an XCD (A/B strips stay
// L2-resident). mfma(bfr, afr) -> lane owns 4 consecutive k-cols -> 8B stores.
__global__ __launch_bounds__(256) void tri_kernel(
    const __bf16* __restrict__ a_t, const __bf16* __restrict__ b_t, __bf16* __restrict__ p_t)
{
  __shared__ __bf16 As[128 * 64];
  __shared__ __bf16 Bs[128 * 64];
  int id = blockIdx.x;
  int xcd = id & 7;
  int k   = id >> 3;                 // 0..143
  int c   = ((k / 9) << 3) + xcd;    // channel 0..127
  int t   = k % 9;
  int i0 = (t / 3) * 128, k0 = (t % 3) * 128;
  const __bf16* Ab = a_t + (size_t)c * NN;
  const __bf16* Bb = b_t + (size_t)c * NN;
  int tid = threadIdx.x, wv = tid >> 6, lane = tid & 63;
  int lm = lane & 15, lq = lane >> 4;
  int lrow = lane >> 3;
  int lsl  = lane & 7;
  int lch  = lsl ^ lrow;
  f32x4 acc[4][4];
#pragma unroll
  for (int mi = 0; mi < 4; ++mi)
#pragma unroll
    for (int ni = 0; ni < 4; ++ni) acc[mi][ni] = {0.f, 0.f, 0.f, 0.f};
  const int rowA_half = 64 * (wv & 1), colB_half = 64 * (wv >> 1);

  for (int kk = 0; kk < 384; kk += 64) {
    __syncthreads();
#pragma unroll
    for (int v = 0; v < 4; ++v) {
      int rgrp = 4 * wv + v;
      int r = 8 * rgrp + lrow;
      load16_to_lds(Ab + (size_t)(i0 + r) * NS + kk + lch * 8, As + rgrp * 512);
      load16_to_lds(Bb + (size_t)(k0 + r) * NS + kk + lch * 8, Bs + rgrp * 512);
    }
    __syncthreads();
#pragma unroll
    for (int s = 0; s < 2; ++s) {
      bf16x8 bfr[4], afr[4];
#pragma unroll
      for (int ni = 0; ni < 4; ++ni)
        bfr[ni] = *(const bf16x8*)(Bs + (colB_half + 16 * ni + lm) * 64 +
                                   ((4 * s + lq) ^ (lm & 7)) * 8);
#pragma unroll
      for (int mi = 0; mi < 4; ++mi)
        afr[mi] = *(const bf16x8*)(As + (rowA_half + 16 * mi + lm) * 64 +
                                   ((4 * s + lq) ^ (lm & 7)) * 8);
      // D = mfma(B, A): row dim (4*lq+r) = k-col offset, col dim (lm) = i-row offset
#pragma unroll
      for (int mi = 0; mi < 4; ++mi)
#pragma unroll
        for (int ni = 0; ni < 4; ++ni)
          acc[mi][ni] = __builtin_amdgcn_mfma_f32_16x16x32_bf16(bfr[ni], afr[mi], acc[mi][ni], 0, 0, 0);
    }
  }
#pragma unroll
  for (int mi = 0; mi < 4; ++mi)
#pragma unroll
    for (int ni = 0; ni < 4; ++ni) {
      int row  = i0 + rowA_half + 16 * mi + lm;
      int colb = k0 + colB_half + 16 * ni + 4 * lq;
      union { __bf16 h[4]; uint2 u; } pk;
#pragma unroll
      for (int r = 0; r < 4; ++r) pk.h[r] = (__bf16)acc[mi][ni][r];
      *(uint2*)(p_t + (size_t)c * NN + (size_t)row * NS + colb) = pk.u;
    }
}

// ---------------- K4: LN over c, @w_z + b_z, * g, + z residual ------------------------
// mfma(wzf, af) -> lane owns 4 consecutive channels -> float4 z loads/stores, 8B g loads.
__global__ __launch_bounds__(256) void out_kernel(
    const __bf16* __restrict__ p_t, const __bf16* __restrict__ g_in,
    const float* __restrict__ z_in, float* __restrict__ z_out,
    const float* __restrict__ lnw, const float* __restrict__ lnb,
    const __bf16* __restrict__ wz, const float* __restrict__ bz)
{
  __shared__ __bf16 pl[64][136];
  int tid = threadIdx.x;
  size_t base = (size_t)blockIdx.x * 64;

  {
    int c2 = tid >> 1, hf = tid & 1;
    const __bf16* src = p_t + (size_t)c2 * NN + base + hf * 32;
    bf16x8 v0 = ((const bf16x8*)src)[0];
    bf16x8 v1 = ((const bf16x8*)src)[1];
    bf16x8 v2 = ((const bf16x8*)src)[2];
    bf16x8 v3 = ((const bf16x8*)src)[3];
#pragma unroll
    for (int j = 0; j < 8; ++j) pl[hf * 32 + j][c2] = v0[j];
#pragma unroll
    for (int j = 0; j < 8; ++j) pl[hf * 32 + 8 + j][c2] = v1[j];
#pragma unroll
    for (int j = 0; j < 8; ++j) pl[hf * 32 + 16 + j][c2] = v2[j];
#pragma unroll
    for (int j = 0; j < 8; ++j) pl[hf * 32 + 24 + j][c2] = v3[j];
  }
  __syncthreads();

  {
    int row = tid >> 2, q = tid & 3;
    bf16x8 pv[4];
#pragma unroll
    for (int s = 0; s < 4; ++s) pv[s] = *(const bf16x8*)(&pl[row][q * 32 + 8 * s]);
    float s1 = 0.f, s2 = 0.f;
#pragma unroll
    for (int s = 0; s < 4; ++s)
#pragma unroll
      for (int j = 0; j < 8; ++j) { float f = (float)pv[s][j]; s1 += f; s2 += f * f; }
    s1 += __shfl_xor(s1, 1); s2 += __shfl_xor(s2, 1);
    s1 += __shfl_xor(s1, 2); s2 += __shfl_xor(s2, 2);
    float mean = s1 * (1.0f / 128.0f);
    float var  = s2 * (1.0f / 128.0f) - mean * mean;
    float rstd = rsqrtf(var + 1e-5f);
#pragma unroll
    for (int s = 0; s < 4; ++s) {
#pragma unroll
      for (int j = 0; j < 8; ++j) {
        int cc = q * 32 + 8 * s + j;
        float f = ((float)pv[s][j] - mean) * rstd * lnw[cc] + lnb[cc];
        pv[s][j] = (__bf16)f;
      }
      *(bf16x8*)(&pl[row][q * 32 + 8 * s]) = pv[s];
    }
  }
  __syncthreads();

  int wv = tid >> 6, lane = tid & 63, lm = lane & 15, lq = lane >> 4;
  bf16x8 wzf[2][4];
#pragma unroll
  for (int nbi = 0; nbi < 2; ++nbi)
#pragma unroll
    for (int s = 0; s < 4; ++s)
      wzf[nbi][s] = *(const bf16x8*)(wz + ((size_t)((s * 8 + 2 * wv + nbi) * 64 + lane)) * 8);
#pragma unroll
  for (int mt = 0; mt < 4; ++mt) {
    bf16x8 af[4];
#pragma unroll
    for (int s = 0; s < 4; ++s)
      af[s] = *(const bf16x8*)(&pl[16 * mt + lm][32 * s + 8 * lq]);
#pragma unroll
    for (int nbi = 0; nbi < 2; ++nbi) {
      f32x4 acc = {0.f, 0.f, 0.f, 0.f};
#pragma unroll
      for (int s = 0; s < 4; ++s)
        acc = __builtin_amdgcn_mfma_f32_16x16x32_bf16(wzf[nbi][s], af[s], acc, 0, 0, 0);
      int pos = 16 * mt + lm;
      int c0 = 16 * (2 * wv + nbi) + 4 * lq;
      size_t idx = (base + pos) * 128 + c0;
      float4 z4 = *(const float4*)(z_in + idx);
      float4 b4 = *(const float4*)(bz + c0);
      union { __bf16 h[4]; uint2 u; } gv;
      gv.u = *(const uint2*)(g_in + idx);
      float4 res;
      res.x = (acc[0] + b4.x) * (float)gv.h[0] + z4.x;
      res.y = (acc[1] + b4.y) * (float)gv.h[1] + z4.y;
      res.z = (acc[2] + b4.z) * (float)gv.h[2] + z4.z;
      res.w = (acc[3] + b4.w) * (float)gv.h[3] + z4.w;
      *(float4*)(z_out + idx) = res;
    }
  }
}

extern "C" void kernel_launch(void* const* d_in, const int* in_sizes, int n_in,
                              void* d_out, int out_size, void* d_ws, size_t ws_size,
                              hipStream_t stream) {
  (void)in_sizes; (void)n_in; (void)out_size; (void)ws_size;
  const float* z        = (const float*)d_in[0];
  const float* ln_in_w  = (const float*)d_in[1];
  const float* ln_in_b  = (const float*)d_in[2];
  const float* w_ag     = (const float*)d_in[3];
  const float* b_ag     = (const float*)d_in[4];
  const float* w_ap     = (const float*)d_in[5];
  const float* b_ap     = (const float*)d_in[6];
  const float* w_bg     = (const float*)d_in[7];
  const float* b_bg     = (const float*)d_in[8];
  const float* w_bp     = (const float*)d_in[9];
  const float* b_bp     = (const float*)d_in[10];
  const float* ln_out_w = (const float*)d_in[11];
  const float* ln_out_b = (const float*)d_in[12];
  const float* w_z      = (const float*)d_in[13];
  const float* b_z      = (const float*)d_in[14];
  const float* w_g      = (const float*)d_in[15];
  const float* b_g      = (const float*)d_in[16];
  float* out = (float*)d_out;

  __bf16* wsw  = (__bf16*)d_ws;             // 12 * 16384 elements
  __bf16* a_t  = wsw + 12 * 16384;
  __bf16* b_t  = a_t + (size_t)NN * 128;
  __bf16* g_b  = b_t + (size_t)NN * 128;
  __bf16* znpt = g_b + (size_t)NN * 128;    // zn during proj, p_t after tri

  prep_weights<<<96, 256, 0, stream>>>(w_ag, w_ap, w_bg, w_bp, w_g, w_z, wsw);

  for (int idx = 0; idx < 2; ++idx) {
    const float* zsrc = (idx == 0) ? z : out;
    const __bf16* wsw5 = wsw + (size_t)idx * 6 * 16384;
    ln_kernel<<<2304, 256, 0, stream>>>(zsrc, ln_in_w + idx * 128, ln_in_b + idx * 128,
                                        znpt, idx);
    proj3_kernel<<<864, 256, 0, stream>>>(
        znpt, wsw5,
        b_ag + idx * 128, b_ap + idx * 128, b_bg + idx * 128, b_bp + idx * 128,
        b_g + idx * 128, a_t, b_t, g_b, idx);
    tri_kernel<<<1152, 256, 0, stream>>>(a_t, b_t, znpt);
    out_kernel<<<2304, 256, 0, stream>>>(
        znpt, g_b, zsrc, out, ln_out_w + idx * 128, ln_out_b + idx * 128,
        wsw5 + 5 * 16384, b_z + idx * 128);
  }
}